// Round 6
// baseline (157.593 us; speedup 1.0000x reference)
//
#include <hip/hip_runtime.h>

#define T_ROWS     16384
#define D_COLS     4096
#define D4         1024        // float4 columns per row
#define QD_DIM     256
#define H_DIM      128
#define NCHUNK     256         // stream blocks; each owns 64 contiguous rows (1 MB)
#define ROWS_PER   64
#define NFIN       128         // finale roles (last 128 finishers)
#define FIN_THRESH (NCHUNK - NFIN)

typedef float vf4 __attribute__((ext_vector_type(4)));

// ws scalar slots (after the two partial arrays): counter, counter2, es, ec
// ---------------------------------------------------------------------------
// Fused kernel. grid = NCHUNK+1 blocks x 512 threads.
//  - bid < NCHUNK: stream 1 MB contiguous chunk -> per-column partial sums;
//    last NFIN finishers spin until all partials visible, then reduce to
//    energies; 128th finisher writes out[0] = ec/es.
//  - bid == NCHUNK: threshold MLP -> out[1] (independent of E_s).
// ---------------------------------------------------------------------------
__global__ void __launch_bounds__(512)
fused_kernel(const float* __restrict__ E_s, const float* __restrict__ att,
             const float* __restrict__ E_q, const float* __restrict__ W1,
             const float* __restrict__ b1, const float* __restrict__ W2,
             const float* __restrict__ b2,
             float* __restrict__ s_part, float* __restrict__ c_part,
             int* __restrict__ counters, float* __restrict__ energies,
             float* __restrict__ out) {
    const int tid = threadIdx.x;
    const int bid = blockIdx.x;

    if (bid == NCHUNK) {
        // ---- threshold MLP (hidden under the streaming) ----
        __shared__ float eq[QD_DIM];
        if (tid < QD_DIM) eq[tid] = E_q[tid];
        __syncthreads();
        const int row = tid >> 2;           // 0..127
        const int q   = tid & 3;            // quarter of the 256-dot
        const float4* w4 = reinterpret_cast<const float4*>(W1 + (size_t)row * QD_DIM) + q * 16;
        const float4* e4 = reinterpret_cast<const float4*>(eq) + q * 16;
        float acc = 0.f;
        #pragma unroll
        for (int k = 0; k < 16; ++k) {
            const float4 w = w4[k];
            const float4 e = e4[k];
            acc = fmaf(w.x, e.x, fmaf(w.y, e.y, fmaf(w.z, e.z, fmaf(w.w, e.w, acc))));
        }
        acc += __shfl_xor(acc, 1);
        acc += __shfl_xor(acc, 2);
        const float h = fmaxf(acc + b1[row], 0.f);
        float p = (q == 0) ? W2[row] * h : 0.f;
        #pragma unroll
        for (int o = 32; o > 0; o >>= 1) p += __shfl_down(p, o);
        __shared__ float red[8];
        if ((tid & 63) == 0) red[tid >> 6] = p;
        __syncthreads();
        if (tid == 0) {
            float z = b2[0];
            #pragma unroll
            for (int i = 0; i < 8; ++i) z += red[i];
            out[1] = 1.f / (1.f + expf(-z));
        }
        return;
    }

    // ---- streaming: 64 contiguous rows = 1 MB ----
    const int r0 = bid * ROWS_PER;
    __shared__ float watt[ROWS_PER];
    if (tid < ROWS_PER) watt[tid] = att[r0 + tid];
    __syncthreads();

    const vf4* p = reinterpret_cast<const vf4*>(E_s) + (size_t)r0 * D4;
    vf4 s0 = {0.f, 0.f, 0.f, 0.f}, c0 = s0, s1 = s0, c1 = s0;

    #pragma unroll
    for (int rb = 0; rb < ROWS_PER; rb += 4) {
        vf4 v[8];
        #pragma unroll
        for (int j = 0; j < 8; ++j) {
            const int r  = rb + (j >> 1);
            const int ph = j & 1;           // which half-row this thread covers
            v[j] = __builtin_nontemporal_load(&p[(size_t)r * D4 + ph * 512 + tid]);
        }
        #pragma unroll
        for (int j = 0; j < 8; ++j) {
            const float w = watt[rb + (j >> 1)];
            if ((j & 1) == 0) { s0 += v[j]; c0 += v[j] * w; }
            else              { s1 += v[j]; c1 += v[j] * w; }
        }
    }

    vf4* sp = reinterpret_cast<vf4*>(s_part) + (size_t)bid * D4;
    vf4* cp = reinterpret_cast<vf4*>(c_part) + (size_t)bid * D4;
    sp[tid]       = s0;
    sp[512 + tid] = s1;
    cp[tid]       = c0;
    cp[512 + tid] = c1;
    __threadfence();                        // release partials

    __shared__ int myold;
    if (tid == 0) myold = atomicAdd(&counters[0], 1);
    __syncthreads();
    const int old = myold;
    if (old < FIN_THRESH) return;           // early finishers exit

    // ---- finale role: wait for all partials, reduce 32 columns ----
    if (tid == 0) {
        while (atomicAdd(&counters[0], 0) < NCHUNK)
            __builtin_amdgcn_s_sleep(32);
    }
    __syncthreads();
    __threadfence();                        // acquire

    const int fid   = old - FIN_THRESH;     // 0..127
    const int l     = tid & 7;              // float4-col within role (8 = 32 cols)
    const int slice = tid >> 3;             // 0..63
    const int c4    = fid * 8 + l;

    const vf4* s4  = reinterpret_cast<const vf4*>(s_part);
    const vf4* c4p = reinterpret_cast<const vf4*>(c_part);
    vf4 sA = {0.f, 0.f, 0.f, 0.f}, cA = sA;
    #pragma unroll
    for (int k = slice; k < NCHUNK; k += 64) {
        sA += s4[(size_t)k * D4 + c4];
        cA += c4p[(size_t)k * D4 + c4];
    }
    __shared__ vf4 shs[64][8];
    __shared__ vf4 shc[64][8];
    shs[slice][l] = sA;
    shc[slice][l] = cA;
    __syncthreads();
    #pragma unroll
    for (int st = 32; st > 0; st >>= 1) {
        if (slice < st) {
            shs[slice][l] += shs[slice + st][l];
            shc[slice][l] += shc[slice + st][l];
        }
        __syncthreads();
    }

    float es = 0.f, ec = 0.f;
    if (tid < 8) {
        const vf4 fs = shs[0][tid];
        const vf4 fc = shc[0][tid];
        es = fs.x * fs.x + fs.y * fs.y + fs.z * fs.z + fs.w * fs.w;
        ec = fc.x * fc.x + fc.y * fc.y + fc.z * fc.z + fc.w * fc.w;
    }
    #pragma unroll
    for (int o = 4; o > 0; o >>= 1) {
        es += __shfl_down(es, o);
        ec += __shfl_down(ec, o);
    }
    if (tid == 0) {
        atomicAdd(&energies[0], es);
        atomicAdd(&energies[1], ec);
        __threadfence();
        const int old2 = atomicAdd(&counters[1], 1);
        if (old2 == NFIN - 1) {
            const float tes = atomicAdd(&energies[0], 0.f);  // coherent read
            const float tec = atomicAdd(&energies[1], 0.f);
            out[0] = tec / tes;
        }
    }
}

// ---------------------------------------------------------------------------
extern "C" void kernel_launch(void* const* d_in, const int* in_sizes, int n_in,
                              void* d_out, int out_size, void* d_ws, size_t ws_size,
                              hipStream_t stream) {
    const float* E_s = (const float*)d_in[0];
    const float* E_q = (const float*)d_in[1];
    const float* att = (const float*)d_in[2];
    const float* W1  = (const float*)d_in[3];
    const float* b1  = (const float*)d_in[4];
    const float* W2  = (const float*)d_in[5];
    const float* b2  = (const float*)d_in[6];
    float* out = (float*)d_out;
    float* ws  = (float*)d_ws;

    // ws layout: s_part | c_part | {counter, counter2} | {es, ec}
    float* s_part   = ws;
    float* c_part   = s_part + (size_t)NCHUNK * D_COLS;
    int*   counters = (int*)(c_part + (size_t)NCHUNK * D_COLS);
    float* energies = (float*)(counters + 2);

    hipMemsetAsync(counters, 0, 4 * sizeof(int), stream);  // counters + energies
    fused_kernel<<<NCHUNK + 1, 512, 0, stream>>>(
        E_s, att, E_q, W1, b1, W2, b2, s_part, c_part, counters, energies, out);
}

// Round 7
// 59.688 us; speedup vs baseline: 2.6403x; 2.6403x over previous
//
#include <hip/hip_runtime.h>

#define T_ROWS   16384
#define D_COLS   4096
#define D4       1024          // float4 columns
#define QD_DIM   256
#define H_DIM    128
#define NCHUNK   512
#define ROWS_PER 32            // T_ROWS / NCHUNK
#define NB2      256           // pass-2 blocks (16 cols each)

typedef float vf4 __attribute__((ext_vector_type(4)));

// ---------------------------------------------------------------------------
// Pass 1: partial column sums (plain + weighted). grid (4, NCHUNK+1), 256 thr.
// 2048 stream blocks -> ~8 blocks/CU, 32 waves/CU; 8 x 16B loads in flight
// per wave. Regular loads (L3-allocatable: E_s re-hits across graph replays).
// The extra block (chunk==NCHUNK, bx==0) computes the MLP -> out[1].
// ---------------------------------------------------------------------------
__global__ void __launch_bounds__(256, 8)
pass1_colsums(const float* __restrict__ E_s, const float* __restrict__ att,
              const float* __restrict__ E_q, const float* __restrict__ W1,
              const float* __restrict__ b1, const float* __restrict__ W2,
              const float* __restrict__ b2,
              float* __restrict__ s_part, float* __restrict__ c_part,
              int* __restrict__ counter, float* __restrict__ out) {
    const int tid   = threadIdx.x;
    const int chunk = blockIdx.y;               // 0..NCHUNK

    if (chunk == NCHUNK) {
        // ---- threshold MLP block (hidden under the streaming) ----
        if (blockIdx.x != 0) return;
        __shared__ float eq[QD_DIM];
        eq[tid] = E_q[tid];
        __syncthreads();

        const int row  = tid >> 1;              // 0..127
        const int half = tid & 1;               // 0..1
        const float4* w4 = reinterpret_cast<const float4*>(W1 + (size_t)row * QD_DIM)
                           + half * 32;
        const float4* e4 = reinterpret_cast<const float4*>(eq) + half * 32;
        float acc = 0.f;
        #pragma unroll 8
        for (int k = 0; k < 32; ++k) {
            const float4 w = w4[k];
            const float4 e = e4[k];
            acc = fmaf(w.x, e.x, fmaf(w.y, e.y, fmaf(w.z, e.z, fmaf(w.w, e.w, acc))));
        }
        acc += __shfl_xor(acc, 1);              // combine the two halves
        const float h = fmaxf(acc + b1[row], 0.f);
        float p = half ? 0.f : W2[row] * h;
        #pragma unroll
        for (int o = 32; o > 0; o >>= 1) p += __shfl_down(p, o);
        __shared__ float red[4];
        if ((tid & 63) == 0) red[tid >> 6] = p;
        __syncthreads();
        if (tid == 0) {
            const float z = red[0] + red[1] + red[2] + red[3] + b2[0];
            out[1] = 1.f / (1.f + expf(-z));
        }
        return;
    }

    const int c4 = blockIdx.x * 256 + tid;      // float4 column, 0..1023
    if (c4 == 0 && chunk == 0) *counter = 0;    // re-zero pass-2 counter each call

    const int r0 = chunk * ROWS_PER;
    __shared__ float watt[ROWS_PER];
    if (tid < ROWS_PER) watt[tid] = att[r0 + tid];
    __syncthreads();

    const vf4* p = reinterpret_cast<const vf4*>(E_s) + (size_t)r0 * D4 + c4;
    vf4 s = {0.f, 0.f, 0.f, 0.f};
    vf4 c = {0.f, 0.f, 0.f, 0.f};

    #pragma unroll
    for (int i = 0; i < ROWS_PER / 8; ++i) {
        vf4 v[8];
        #pragma unroll
        for (int j = 0; j < 8; ++j)
            v[j] = p[(size_t)(i * 8 + j) * D4];   // 8 independent 16B loads
        #pragma unroll
        for (int j = 0; j < 8; ++j) {
            const float w = watt[i * 8 + j];
            s += v[j];
            c += v[j] * w;
        }
    }

    const size_t off = (size_t)chunk * D4 + c4;
    reinterpret_cast<vf4*>(s_part)[off] = s;
    reinterpret_cast<vf4*>(c_part)[off] = c;
}

// ---------------------------------------------------------------------------
// Pass 2 + final energies. Block b owns 16 columns (4 float4 cols); threads =
// 4 col4 x 64 chunk-slices (8 iters, 16 float4 loads in flight). LDS tree
// reduce, square, block partial; last block reduces 256 partials -> out[0].
// ---------------------------------------------------------------------------
__global__ void __launch_bounds__(256)
pass2_final(const float* __restrict__ s_part, const float* __restrict__ c_part,
            float* __restrict__ es_part, float* __restrict__ ec_part,
            int* __restrict__ counter, float* __restrict__ out) {
    const int tid   = threadIdx.x;
    const int l     = tid & 3;                  // float4-col within block
    const int slice = tid >> 2;                 // 0..63
    const int c4    = blockIdx.x * 4 + l;       // global float4 col

    const vf4* s4  = reinterpret_cast<const vf4*>(s_part);
    const vf4* c4p = reinterpret_cast<const vf4*>(c_part);

    vf4 sA = {0.f, 0.f, 0.f, 0.f};
    vf4 cA = {0.f, 0.f, 0.f, 0.f};
    #pragma unroll
    for (int k = slice; k < NCHUNK; k += 64) {
        sA += s4[(size_t)k * D4 + c4];
        cA += c4p[(size_t)k * D4 + c4];
    }

    __shared__ vf4 shs[64][4];
    __shared__ vf4 shc[64][4];
    shs[slice][l] = sA;
    shc[slice][l] = cA;
    __syncthreads();

    #pragma unroll
    for (int st = 32; st > 0; st >>= 1) {
        if (slice < st) {
            shs[slice][l] += shs[slice + st][l];
            shc[slice][l] += shc[slice + st][l];
        }
        __syncthreads();
    }

    float es = 0.f, ec = 0.f;
    if (tid < 4) {
        const vf4 fs = shs[0][tid];
        const vf4 fc = shc[0][tid];
        es = fs.x * fs.x + fs.y * fs.y + fs.z * fs.z + fs.w * fs.w;
        ec = fc.x * fc.x + fc.y * fc.y + fc.z * fc.z + fc.w * fc.w;
    }
    #pragma unroll
    for (int o = 32; o > 0; o >>= 1) {
        es += __shfl_down(es, o);
        ec += __shfl_down(ec, o);
    }

    __shared__ int lastflag;
    if (tid == 0) {
        es_part[blockIdx.x] = es;
        ec_part[blockIdx.x] = ec;
        __threadfence();                        // release partials
        lastflag = (atomicAdd(counter, 1) == NB2 - 1);
    }
    __syncthreads();
    if (!lastflag) return;

    // ---- last block: reduce 256 partials, write r ----
    __threadfence();                            // acquire
    float fes = atomicAdd(&es_part[tid], 0.f);  // coherent read-back
    float fec = atomicAdd(&ec_part[tid], 0.f);
    #pragma unroll
    for (int o = 32; o > 0; o >>= 1) {
        fes += __shfl_down(fes, o);
        fec += __shfl_down(fec, o);
    }
    __shared__ float r_es[4], r_ec[4];
    if ((tid & 63) == 0) { r_es[tid >> 6] = fes; r_ec[tid >> 6] = fec; }
    __syncthreads();
    if (tid == 0) {
        const float es_t = r_es[0] + r_es[1] + r_es[2] + r_es[3];
        const float ec_t = r_ec[0] + r_ec[1] + r_ec[2] + r_ec[3];
        out[0] = ec_t / es_t;
    }
}

// ---------------------------------------------------------------------------
extern "C" void kernel_launch(void* const* d_in, const int* in_sizes, int n_in,
                              void* d_out, int out_size, void* d_ws, size_t ws_size,
                              hipStream_t stream) {
    const float* E_s = (const float*)d_in[0];
    const float* E_q = (const float*)d_in[1];
    const float* att = (const float*)d_in[2];
    const float* W1  = (const float*)d_in[3];
    const float* b1  = (const float*)d_in[4];
    const float* W2  = (const float*)d_in[5];
    const float* b2  = (const float*)d_in[6];
    float* out = (float*)d_out;
    float* ws  = (float*)d_ws;

    // ws layout: s_part | c_part | es_part | ec_part | counter  (~16.8 MB)
    float* s_part  = ws;
    float* c_part  = s_part + (size_t)NCHUNK * D_COLS;
    float* es_part = c_part + (size_t)NCHUNK * D_COLS;
    float* ec_part = es_part + NB2;
    int*   counter = (int*)(ec_part + NB2);

    pass1_colsums<<<dim3(4, NCHUNK + 1), 256, 0, stream>>>(
        E_s, att, E_q, W1, b1, W2, b2, s_part, c_part, counter, out);
    pass2_final<<<NB2, 256, 0, stream>>>(s_part, c_part, es_part, ec_part, counter, out);
}

// Round 8
// 53.834 us; speedup vs baseline: 2.9274x; 1.1087x over previous
//
#include <hip/hip_runtime.h>

#define T_ROWS   16384
#define D_COLS   4096
#define D4       1024          // float4 columns
#define QD_DIM   256
#define H_DIM    128
#define NCHUNK   512
#define ROWS_PER 32            // T_ROWS / NCHUNK
#define NB2      64            // pass-2 blocks (16 col4s each)

typedef float vf4 __attribute__((ext_vector_type(4)));

// ---------------------------------------------------------------------------
// Pass 1: grid (4, NCHUNK+1), 256 thr. y==0 is the service row: (0,0) runs the
// threshold MLP (concurrent with streaming, writes out[1]); (1,0) zeroes the
// pass-2 counter + energy accumulators. y>=1 stream chunk y-1: 8 x 16B loads
// in flight per wave, 2048 blocks = 8/CU.
// ---------------------------------------------------------------------------
__global__ void __launch_bounds__(256, 8)
pass1_colsums(const float* __restrict__ E_s, const float* __restrict__ att,
              const float* __restrict__ E_q, const float* __restrict__ W1,
              const float* __restrict__ b1, const float* __restrict__ W2,
              const float* __restrict__ b2,
              float* __restrict__ s_part, float* __restrict__ c_part,
              int* __restrict__ counter, float* __restrict__ energies,
              float* __restrict__ out) {
    const int tid = threadIdx.x;

    if (blockIdx.y == 0) {
        if (blockIdx.x == 1) {
            if (tid == 0) { counter[0] = 0; energies[0] = 0.f; energies[1] = 0.f; }
            return;
        }
        if (blockIdx.x != 0) return;
        // ---- threshold MLP (hidden under the streaming) ----
        __shared__ float eq[QD_DIM];
        eq[tid] = E_q[tid];
        __syncthreads();
        const int row  = tid >> 1;              // 0..127
        const int half = tid & 1;
        const float4* w4 = reinterpret_cast<const float4*>(W1 + (size_t)row * QD_DIM)
                           + half * 32;
        const float4* e4 = reinterpret_cast<const float4*>(eq) + half * 32;
        float acc = 0.f;
        #pragma unroll 8
        for (int k = 0; k < 32; ++k) {
            const float4 w = w4[k];
            const float4 e = e4[k];
            acc = fmaf(w.x, e.x, fmaf(w.y, e.y, fmaf(w.z, e.z, fmaf(w.w, e.w, acc))));
        }
        acc += __shfl_xor(acc, 1);
        const float h = fmaxf(acc + b1[row], 0.f);
        float p = half ? 0.f : W2[row] * h;
        #pragma unroll
        for (int o = 32; o > 0; o >>= 1) p += __shfl_down(p, o);
        __shared__ float red[4];
        if ((tid & 63) == 0) red[tid >> 6] = p;
        __syncthreads();
        if (tid == 0) {
            const float z = red[0] + red[1] + red[2] + red[3] + b2[0];
            out[1] = 1.f / (1.f + expf(-z));
        }
        return;
    }

    // ---- streaming ----
    const int chunk = blockIdx.y - 1;           // 0..NCHUNK-1
    const int c4    = blockIdx.x * 256 + tid;   // float4 column, 0..1023
    const int r0    = chunk * ROWS_PER;

    __shared__ float watt[ROWS_PER];
    if (tid < ROWS_PER) watt[tid] = att[r0 + tid];
    __syncthreads();

    const vf4* p = reinterpret_cast<const vf4*>(E_s) + (size_t)r0 * D4 + c4;
    vf4 s = {0.f, 0.f, 0.f, 0.f};
    vf4 c = {0.f, 0.f, 0.f, 0.f};

    #pragma unroll
    for (int i = 0; i < ROWS_PER / 8; ++i) {
        vf4 v[8];
        #pragma unroll
        for (int j = 0; j < 8; ++j)
            v[j] = p[(size_t)(i * 8 + j) * D4];   // 8 independent 16B loads
        #pragma unroll
        for (int j = 0; j < 8; ++j) {
            const float w = watt[i * 8 + j];
            s += v[j];
            c += v[j] * w;
        }
    }

    const size_t off = (size_t)chunk * D4 + c4;
    reinterpret_cast<vf4*>(s_part)[off] = s;
    reinterpret_cast<vf4*>(c_part)[off] = c;
}

// ---------------------------------------------------------------------------
// Pass 2 + finale. 64 blocks x 256 thr. Thread (w=tid>>6, L=tid&63) owns
// col4 = b*16 + (L&15) and chunk-phase (L>>4)+4w; k = phase + 16*i, i<32.
// Wave-loads are 4 x 256B segments. LDS[16][16] combine -> full column sums
// -> square -> wave reduce -> atomicAdd energies; last block writes out[0].
// ---------------------------------------------------------------------------
__global__ void __launch_bounds__(256)
pass2_final(const float* __restrict__ s_part, const float* __restrict__ c_part,
            float* __restrict__ energies, int* __restrict__ counter,
            float* __restrict__ out) {
    const int tid    = threadIdx.x;
    const int L      = tid & 63;
    const int w      = tid >> 6;
    const int c4     = blockIdx.x * 16 + (L & 15);
    const int kphase = (L >> 4) + 4 * w;        // 0..15

    const vf4* s4  = reinterpret_cast<const vf4*>(s_part);
    const vf4* c4p = reinterpret_cast<const vf4*>(c_part);

    vf4 sA = {0.f, 0.f, 0.f, 0.f};
    vf4 cA = {0.f, 0.f, 0.f, 0.f};
    #pragma unroll 8
    for (int i = 0; i < NCHUNK / 16; ++i) {
        const int k = kphase + 16 * i;
        sA += s4[(size_t)k * D4 + c4];
        cA += c4p[(size_t)k * D4 + c4];
    }

    __shared__ vf4 sh_s[16][16];
    __shared__ vf4 sh_c[16][16];
    sh_s[kphase][L & 15] = sA;
    sh_c[kphase][L & 15] = cA;
    __syncthreads();

    float es = 0.f, ec = 0.f;
    if (tid < 16) {
        vf4 S = {0.f, 0.f, 0.f, 0.f};
        vf4 C = {0.f, 0.f, 0.f, 0.f};
        #pragma unroll
        for (int ph = 0; ph < 16; ++ph) { S += sh_s[ph][tid]; C += sh_c[ph][tid]; }
        es = S.x * S.x + S.y * S.y + S.z * S.z + S.w * S.w;
        ec = C.x * C.x + C.y * C.y + C.z * C.z + C.w * C.w;
    }
    #pragma unroll
    for (int o = 8; o > 0; o >>= 1) {
        es += __shfl_down(es, o);
        ec += __shfl_down(ec, o);
    }

    if (tid == 0) {
        atomicAdd(&energies[0], es);
        atomicAdd(&energies[1], ec);
        __threadfence();
        const int old = atomicAdd(counter, 1);
        if (old == NB2 - 1) {
            const float tes = atomicAdd(&energies[0], 0.f);  // coherent read-back
            const float tec = atomicAdd(&energies[1], 0.f);
            out[0] = tec / tes;
        }
    }
}

// ---------------------------------------------------------------------------
extern "C" void kernel_launch(void* const* d_in, const int* in_sizes, int n_in,
                              void* d_out, int out_size, void* d_ws, size_t ws_size,
                              hipStream_t stream) {
    const float* E_s = (const float*)d_in[0];
    const float* E_q = (const float*)d_in[1];
    const float* att = (const float*)d_in[2];
    const float* W1  = (const float*)d_in[3];
    const float* b1  = (const float*)d_in[4];
    const float* W2  = (const float*)d_in[5];
    const float* b2  = (const float*)d_in[6];
    float* out = (float*)d_out;
    float* ws  = (float*)d_ws;

    // ws layout: s_part | c_part | energies[2] | counter  (~16.8 MB)
    float* s_part   = ws;
    float* c_part   = s_part + (size_t)NCHUNK * D_COLS;
    float* energies = c_part + (size_t)NCHUNK * D_COLS;
    int*   counter  = (int*)(energies + 2);

    pass1_colsums<<<dim3(4, NCHUNK + 1), 256, 0, stream>>>(
        E_s, att, E_q, W1, b1, W2, b2, s_part, c_part, counter, energies, out);
    pass2_final<<<NB2, 256, 0, stream>>>(s_part, c_part, energies, counter, out);
}